// Round 1
// baseline (258.857 us; speedup 1.0000x reference)
//
#include <hip/hip_runtime.h>

typedef __bf16 bf16x8 __attribute__((ext_vector_type(8)));
typedef float f32x4 __attribute__((ext_vector_type(4)));

#define DEV __device__ __forceinline__

// ---------- helpers ----------
DEV unsigned short f2bf(float f) {  // round-to-nearest-even f32 -> bf16
  unsigned u = __float_as_uint(f);
  u += 0x7fffu + ((u >> 16) & 1u);
  return (unsigned short)(u >> 16);
}
DEV float bf2f(unsigned short h) { return __uint_as_float(((unsigned)h) << 16); }

DEV void gload16(const void* g, void* l) {
  // async global->LDS, 16B per lane; LDS dest = wave-uniform base + lane*16
  __builtin_amdgcn_global_load_lds((const __attribute__((address_space(1))) void*)g,
                                   (__attribute__((address_space(3))) void*)l, 16, 0, 0);
}

// ---------- fp32 -> bf16 convert ----------
__global__ __launch_bounds__(256) void cvt_bf16(const float4* __restrict__ src,
                                                ushort4* __restrict__ dst, int n4) {
  int i = blockIdx.x * blockDim.x + threadIdx.x;
  const int stride = gridDim.x * blockDim.x;
  for (; i < n4; i += stride) {
    float4 v = src[i];
    ushort4 o;
    o.x = f2bf(v.x); o.y = f2bf(v.y); o.z = f2bf(v.z); o.w = f2bf(v.w);
    dst[i] = o;
  }
}

// ---------- GEMM: C[m][n] = sum_k A[m][k] * B[n][k]  (M=4096, N=1024, K=1024) ----------
// BM=128, BN=64, BK=32. 4 waves: 2x2 wave grid, each wave 64x32 (4x2 16x16 frags).
// Double-buffered LDS, single barrier per K-step (staging overlaps compute).
template <typename OUT_T>
__global__ __launch_bounds__(256) void gemm_bt(const unsigned short* __restrict__ A,
                                               const unsigned short* __restrict__ Bw,
                                               OUT_T* __restrict__ C) {
  __shared__ char sA[2][8192];  // [128][32] bf16
  __shared__ char sB[2][4096];  // [64][32] bf16
  const int tid = threadIdx.x;
  const int w = tid >> 6, lane = tid & 63;
  const int bm = blockIdx.y, bn = blockIdx.x;
  const int wm = w >> 1, wn = w & 1;

  f32x4 acc[4][2];
#pragma unroll
  for (int i = 0; i < 4; ++i)
#pragma unroll
    for (int j = 0; j < 2; ++j) acc[i][j] = (f32x4){0.f, 0.f, 0.f, 0.f};

  // staging sources (row-major, K=1024 -> 2048 B/row); advance 64 B per K-step
  const char* aS0 = (const char*)A + ((size_t)(bm * 128 + w * 32 + (lane >> 2)) << 11) + (lane & 3) * 16;
  const char* aS1 = aS0 + (16 << 11);
  const char* bS  = (const char*)Bw + ((size_t)(bn * 64 + w * 16 + (lane >> 2)) << 11) + (lane & 3) * 16;

  // fragment read bases (within a 32-col = 64 B row tile)
  const int aRoff = (wm * 64 + (lane & 15)) * 64 + ((lane >> 4) << 4);
  const int bRoff = (wn * 32 + (lane & 15)) * 64 + ((lane >> 4) << 4);

  // prologue: stage k-tile 0 into buffer 0
  gload16(aS0, &sA[0][(w * 2 + 0) * 1024]);
  gload16(aS1, &sA[0][(w * 2 + 1) * 1024]);
  gload16(bS, &sB[0][w * 1024]);
  aS0 += 64; aS1 += 64; bS += 64;

  for (int kt = 0; kt < 32; ++kt) {
    const int cur = kt & 1;
    __syncthreads();  // buf[cur] staged (drains vmcnt)
    if (kt < 31) {    // stage next tile; overlaps the MFMA work below
      gload16(aS0, &sA[cur ^ 1][(w * 2 + 0) * 1024]);
      gload16(aS1, &sA[cur ^ 1][(w * 2 + 1) * 1024]);
      gload16(bS, &sB[cur ^ 1][w * 1024]);
      aS0 += 64; aS1 += 64; bS += 64;
    }
    bf16x8 aF[4], bF[2];
#pragma unroll
    for (int mi = 0; mi < 4; ++mi) aF[mi] = *(const bf16x8*)(&sA[cur][aRoff + mi * 16 * 64]);
#pragma unroll
    for (int ni = 0; ni < 2; ++ni) bF[ni] = *(const bf16x8*)(&sB[cur][bRoff + ni * 16 * 64]);
#pragma unroll
    for (int mi = 0; mi < 4; ++mi)
#pragma unroll
      for (int ni = 0; ni < 2; ++ni)
        acc[mi][ni] = __builtin_amdgcn_mfma_f32_16x16x32_bf16(aF[mi], bF[ni], acc[mi][ni], 0, 0, 0);
  }

  // epilogue: D row = (lane>>4)*4 + reg, col = lane&15
  const int r0 = bm * 128 + wm * 64 + ((lane >> 4) << 2);
  const int c0 = bn * 64 + wn * 32 + (lane & 15);
#pragma unroll
  for (int mi = 0; mi < 4; ++mi)
#pragma unroll
    for (int ni = 0; ni < 2; ++ni)
#pragma unroll
      for (int i = 0; i < 4; ++i) {
        size_t idx = (size_t)(r0 + mi * 16 + i) * 1024 + (c0 + ni * 16);
        if constexpr (sizeof(OUT_T) == 4)
          C[idx] = acc[mi][ni][i];
        else
          C[idx] = f2bf(acc[mi][ni][i]);
      }
}

// ---------- per-head LayerNorm + packed/swizzled tile layout ----------
// In:  Y bf16 [B*N][1024]  (head h = cols [h*64, h*64+64))
// Out: packed [bh][t][r][swizzled 128B row]; element (r, cbyte) at byte
//      ((bh*32+t)*64 + r)*128 + (cbyte ^ ((r&7)<<4)).  oscale folds muP 0.125 into Q.
__global__ __launch_bounds__(256) void ln_pack(const unsigned short* __restrict__ Y,
                                               unsigned short* __restrict__ P, float oscale) {
  const int tid = threadIdx.x;
  const int rid = blockIdx.x * 32 + (tid >> 3);  // head-row id in [0, 65536)
  const int sub = tid & 7;                       // 8 lanes per row, 8 bf16 each
  const uint4 v = *(const uint4*)(Y + (size_t)rid * 64 + sub * 8);
  float x[8];
  x[0] = bf2f((unsigned short)(v.x & 0xffff)); x[1] = bf2f((unsigned short)(v.x >> 16));
  x[2] = bf2f((unsigned short)(v.y & 0xffff)); x[3] = bf2f((unsigned short)(v.y >> 16));
  x[4] = bf2f((unsigned short)(v.z & 0xffff)); x[5] = bf2f((unsigned short)(v.z >> 16));
  x[6] = bf2f((unsigned short)(v.w & 0xffff)); x[7] = bf2f((unsigned short)(v.w >> 16));
  float s = 0.f, ss = 0.f;
#pragma unroll
  for (int j = 0; j < 8; ++j) { s += x[j]; ss += x[j] * x[j]; }
#pragma unroll
  for (int msk = 1; msk <= 4; msk <<= 1) {
    s += __shfl_xor(s, msk);
    ss += __shfl_xor(ss, msk);
  }
  const float mean = s * 0.015625f;
  const float var = ss * 0.015625f - mean * mean;
  const float rstd = rsqrtf(var + 1e-5f) * oscale;
  unsigned o[4];
#pragma unroll
  for (int j = 0; j < 4; ++j) {
    unsigned lo = f2bf((x[2 * j] - mean) * rstd);
    unsigned hi = f2bf((x[2 * j + 1] - mean) * rstd);
    o[j] = lo | (hi << 16);
  }
  const int b = rid >> 15, n = (rid >> 4) & 2047, h = rid & 15;
  const int bh = b * 16 + h, t = n >> 6, r = n & 63;
  char* dst = (char*)P + (((size_t)(bh * 32 + t) * 64 + r) << 7) + ((sub * 16) ^ ((r & 7) << 4));
  *(uint4*)dst = make_uint4(o[0], o[1], o[2], o[3]);
}

// ---------- V transpose + pack:  VT[bh][t][d][n-swizzled] ----------
__global__ __launch_bounds__(256) void vt_pack(const unsigned short* __restrict__ Y,
                                               unsigned short* __restrict__ VT) {
  const int bh = blockIdx.x >> 5, t = blockIdx.x & 31;
  const int b = bh >> 4, h = bh & 15;
  __shared__ unsigned short tile[64][72];  // [n][d], padded
  const int tid = threadIdx.x;
#pragma unroll
  for (int it = 0; it < 2; ++it) {
    const int cid = it * 256 + tid;
    const int nl = cid >> 3, dc = cid & 7;
    const uint4 v = *(const uint4*)(Y + ((size_t)(b * 2048 + t * 64 + nl) * 1024 + h * 64 + dc * 8));
    *(uint4*)&tile[nl][dc * 8] = v;
  }
  __syncthreads();
#pragma unroll
  for (int it = 0; it < 2; ++it) {
    const int cid = it * 256 + tid;
    const int d = cid >> 3, nc = cid & 7;
    unsigned o[4];
#pragma unroll
    for (int j = 0; j < 4; ++j)
      o[j] = (unsigned)tile[nc * 8 + 2 * j][d] | ((unsigned)tile[nc * 8 + 2 * j + 1][d] << 16);
    char* dst = (char*)VT + (((size_t)(bh * 32 + t) * 64 + d) << 7) + ((nc * 16) ^ ((d & 7) << 4));
    *(uint4*)dst = make_uint4(o[0], o[1], o[2], o[3]);
  }
}

// ---------- flash attention ----------
// grid (16 qt, 32 bh), 256 threads (4 waves x 32 q-rows). KV tile = 64.
__global__ __launch_bounds__(256) void attn_fused(const unsigned short* __restrict__ Qp,
                                                  const unsigned short* __restrict__ Kp,
                                                  const unsigned short* __restrict__ Vp,
                                                  unsigned short* __restrict__ O) {
  const int qt = blockIdx.x, bh = blockIdx.y;
  const int b = bh >> 4, h = bh & 15;
  __shared__ char sQ[16384];    // 2 Q tiles; reused as P after Q frags in regs
  __shared__ char sK[2][8192];  // K tile dbuf
  __shared__ char sV[2][8192];  // V^T tile dbuf
  const int tid = threadIdx.x, w = tid >> 6, lane = tid & 63;

  const char* qg = (const char*)Qp + ((size_t)bh * 32 + qt * 2) * 8192;
  const char* kg = (const char*)Kp + (size_t)bh * 32 * 8192;
  const char* vg = (const char*)Vp + (size_t)bh * 32 * 8192;

  // prologue: stage Q (16KB) + K0/V0
#pragma unroll
  for (int t = 0; t < 4; ++t)
    gload16(qg + (w * 4 + t) * 1024 + lane * 16, sQ + (w * 4 + t) * 1024);
#pragma unroll
  for (int t = 0; t < 2; ++t) {
    gload16(kg + (w * 2 + t) * 1024 + lane * 16, &sK[0][(w * 2 + t) * 1024]);
    gload16(vg + (w * 2 + t) * 1024 + lane * 16, &sV[0][(w * 2 + t) * 1024]);
  }
  __syncthreads();

  // Q fragments -> registers (wave-private rows [w*32, w*32+32))
  bf16x8 qf[2][2];
#pragma unroll
  for (int m = 0; m < 2; ++m) {
    const int ql = w * 32 + m * 16 + (lane & 15);
    const int tt = ql >> 6, r = ql & 63;
#pragma unroll
    for (int kc = 0; kc < 2; ++kc) {
      const int cb = kc * 64 + ((lane >> 4) << 4);
      qf[m][kc] = *(const bf16x8*)(sQ + tt * 8192 + r * 128 + (cb ^ ((r & 7) << 4)));
    }
  }
  __syncthreads();  // Q region now reusable as P
  char* sP = sQ;

  f32x4 of[2][4];
  float rm[2][4], rl[2][4];
#pragma unroll
  for (int m = 0; m < 2; ++m)
#pragma unroll
    for (int i = 0; i < 4; ++i) {
      rm[m][i] = -1e30f;
      rl[m][i] = 0.f;
      if (i == 0) {}
    }
#pragma unroll
  for (int m = 0; m < 2; ++m)
#pragma unroll
    for (int n = 0; n < 4; ++n) of[m][n] = (f32x4){0.f, 0.f, 0.f, 0.f};

  for (int kt = 0; kt < 32; ++kt) {
    const int cur = kt & 1;
    if (kt + 1 < 32) {  // prefetch next KV tile; drained by end-of-loop barrier
#pragma unroll
      for (int t = 0; t < 2; ++t) {
        gload16(kg + (size_t)(kt + 1) * 8192 + (w * 2 + t) * 1024 + lane * 16,
                &sK[cur ^ 1][(w * 2 + t) * 1024]);
        gload16(vg + (size_t)(kt + 1) * 8192 + (w * 2 + t) * 1024 + lane * 16,
                &sV[cur ^ 1][(w * 2 + t) * 1024]);
      }
    }
    // S = Q*K^T (scale folded into Q)
    f32x4 s[2][4];
#pragma unroll
    for (int m = 0; m < 2; ++m)
#pragma unroll
      for (int n = 0; n < 4; ++n) s[m][n] = (f32x4){0.f, 0.f, 0.f, 0.f};
#pragma unroll
    for (int n = 0; n < 4; ++n) {
      const int r = n * 16 + (lane & 15);
#pragma unroll
      for (int kc = 0; kc < 2; ++kc) {
        const int cb = kc * 64 + ((lane >> 4) << 4);
        bf16x8 kf = *(const bf16x8*)(&sK[cur][r * 128 + (cb ^ ((r & 7) << 4))]);
#pragma unroll
        for (int m = 0; m < 2; ++m)
          s[m][n] = __builtin_amdgcn_mfma_f32_16x16x32_bf16(qf[m][kc], kf, s[m][n], 0, 0, 0);
      }
    }
    // online softmax (row = (lane>>4)*4 + i within each 16-frag; reduce over 16-lane group)
#pragma unroll
    for (int m = 0; m < 2; ++m)
#pragma unroll
      for (int i = 0; i < 4; ++i) {
        float mx = fmaxf(fmaxf(s[m][0][i], s[m][1][i]), fmaxf(s[m][2][i], s[m][3][i]));
#pragma unroll
        for (int msk = 1; msk <= 8; msk <<= 1) mx = fmaxf(mx, __shfl_xor(mx, msk));
        const float mo = rm[m][i];
        const float mn = fmaxf(mo, mx);
        const float corr = __expf(mo - mn);
        rm[m][i] = mn;
        float p[4], rs = 0.f;
#pragma unroll
        for (int n = 0; n < 4; ++n) {
          p[n] = __expf(s[m][n][i] - mn);
          rs += p[n];
        }
#pragma unroll
        for (int msk = 1; msk <= 8; msk <<= 1) rs += __shfl_xor(rs, msk);
        rl[m][i] = rl[m][i] * corr + rs;
#pragma unroll
        for (int n = 0; n < 4; ++n) of[m][n][i] *= corr;
        const int r = w * 32 + m * 16 + ((lane >> 4) << 2) + i;
#pragma unroll
        for (int n = 0; n < 4; ++n) {
          const int cb = (n * 16 + (lane & 15)) * 2;
          *(unsigned short*)(sP + r * 128 + (cb ^ ((r & 7) << 4))) = f2bf(p[n]);
        }
      }
    // PV: O += P * V   (P rows are wave-private; same-wave LDS RAW is in-order)
#pragma unroll
    for (int kc = 0; kc < 2; ++kc) {
      const int cb = kc * 64 + ((lane >> 4) << 4);
      bf16x8 pa[2];
#pragma unroll
      for (int m = 0; m < 2; ++m) {
        const int r = w * 32 + m * 16 + (lane & 15);
        pa[m] = *(const bf16x8*)(sP + r * 128 + (cb ^ ((r & 7) << 4)));
      }
#pragma unroll
      for (int nd = 0; nd < 4; ++nd) {
        const int r = nd * 16 + (lane & 15);
        bf16x8 vf = *(const bf16x8*)(&sV[cur][r * 128 + (cb ^ ((r & 7) << 4))]);
#pragma unroll
        for (int m = 0; m < 2; ++m)
          of[m][nd] = __builtin_amdgcn_mfma_f32_16x16x32_bf16(pa[m], vf, of[m][nd], 0, 0, 0);
      }
    }
    __syncthreads();  // KV prefetch drained; everyone done with buf[cur] and P
  }

  // epilogue: O[b][n][h*64+d] bf16
#pragma unroll
  for (int m = 0; m < 2; ++m)
#pragma unroll
    for (int i = 0; i < 4; ++i) {
      const float inv = 1.f / rl[m][i];
      const int qn = qt * 128 + w * 32 + m * 16 + ((lane >> 4) << 2) + i;
#pragma unroll
      for (int n = 0; n < 4; ++n) {
        const int col = h * 64 + n * 16 + (lane & 15);
        O[(size_t)(b * 2048 + qn) * 1024 + col] = f2bf(of[m][n][i] * inv);
      }
    }
}

// ---------- launch ----------
extern "C" void kernel_launch(void* const* d_in, const int* in_sizes, int n_in,
                              void* d_out, int out_size, void* d_ws, size_t ws_size,
                              hipStream_t stream) {
  const float* xq = (const float*)d_in[0];
  const float* xk = (const float*)d_in[1];
  const float* xv = (const float*)d_in[2];
  const float* wq = (const float*)d_in[3];
  const float* wk = (const float*)d_in[4];
  const float* wv = (const float*)d_in[5];
  const float* wp = (const float*)d_in[6];

  const size_t NX = 4194304;  // B*N*D
  const size_t NW = 1048576;  // D*D
  unsigned short* xqb = (unsigned short*)d_ws;
  unsigned short* xkb = xqb + NX;
  unsigned short* xvb = xkb + NX;
  unsigned short* wqb = xvb + NX;
  unsigned short* wkb = wqb + NW;
  unsigned short* wvb = wkb + NW;
  unsigned short* wpb = wvb + NW;
  unsigned short* ybuf = wpb + NW;
  unsigned short* qh = ybuf + NX;
  unsigned short* kh = qh + NX;
  unsigned short* vt = kh + NX;
  unsigned short* obf = vt + NX;

  cvt_bf16<<<1024, 256, 0, stream>>>((const float4*)xq, (ushort4*)xqb, (int)(NX / 4));
  cvt_bf16<<<1024, 256, 0, stream>>>((const float4*)xk, (ushort4*)xkb, (int)(NX / 4));
  cvt_bf16<<<1024, 256, 0, stream>>>((const float4*)xv, (ushort4*)xvb, (int)(NX / 4));
  cvt_bf16<<<512, 256, 0, stream>>>((const float4*)wq, (ushort4*)wqb, (int)(NW / 4));
  cvt_bf16<<<512, 256, 0, stream>>>((const float4*)wk, (ushort4*)wkb, (int)(NW / 4));
  cvt_bf16<<<512, 256, 0, stream>>>((const float4*)wv, (ushort4*)wvb, (int)(NW / 4));
  cvt_bf16<<<512, 256, 0, stream>>>((const float4*)wp, (ushort4*)wpb, (int)(NW / 4));

  const dim3 gg(16, 32);  // (N/64, M/128)
  gemm_bt<unsigned short><<<gg, 256, 0, stream>>>(xqb, wqb, ybuf);
  ln_pack<<<2048, 256, 0, stream>>>(ybuf, qh, 0.125f);
  gemm_bt<unsigned short><<<gg, 256, 0, stream>>>(xkb, wkb, ybuf);
  ln_pack<<<2048, 256, 0, stream>>>(ybuf, kh, 1.0f);
  gemm_bt<unsigned short><<<gg, 256, 0, stream>>>(xvb, wvb, ybuf);
  vt_pack<<<1024, 256, 0, stream>>>(ybuf, vt);

  attn_fused<<<dim3(16, 32), 256, 0, stream>>>(qh, kh, vt, obf);

  gemm_bt<float><<<gg, 256, 0, stream>>>(obf, wpb, (float*)d_out);
}

// Round 2
// 197.221 us; speedup vs baseline: 1.3125x; 1.3125x over previous
//
#include <hip/hip_runtime.h>

typedef __bf16 bf16x8 __attribute__((ext_vector_type(8)));
typedef float f32x4 __attribute__((ext_vector_type(4)));
typedef float f32x16 __attribute__((ext_vector_type(16)));
typedef unsigned u32x4 __attribute__((ext_vector_type(4)));

#define DEV __device__ __forceinline__
#define L2E 1.44269504f

// ---------- helpers ----------
DEV unsigned short f2bf(float f) {  // round-to-nearest-even f32 -> bf16
  unsigned u = __float_as_uint(f);
  u += 0x7fffu + ((u >> 16) & 1u);
  return (unsigned short)(u >> 16);
}
DEV float bf2f(unsigned short h) { return __uint_as_float(((unsigned)h) << 16); }

DEV void gload16(const void* g, void* l) {
  __builtin_amdgcn_global_load_lds((const __attribute__((address_space(1))) void*)g,
                                   (__attribute__((address_space(3))) void*)l, 16, 0, 0);
}

DEV unsigned cvtpk2(float lo, float hi) {  // dword = {bf16(lo), bf16(hi)<<16}
  unsigned r;
  asm("v_cvt_pk_bf16_f32 %0, %1, %2" : "=v"(r) : "v"(lo), "v"(hi));
  return r;
}
DEV void plswap(unsigned& a, unsigned& b) {  // a.hi_lanes <-> b.lo_lanes
  asm volatile("v_permlane32_swap_b32 %0, %1" : "+v"(a), "+v"(b));
}

// ---------- fp32 -> bf16 converts (consolidated) ----------
DEV void cvt_body(const float4* __restrict__ s, ushort4* __restrict__ d, int n4) {
  for (int i = blockIdx.x * 256 + threadIdx.x; i < n4; i += gridDim.x * 256) {
    float4 v = s[i];
    ushort4 o;
    o.x = f2bf(v.x); o.y = f2bf(v.y); o.z = f2bf(v.z); o.w = f2bf(v.w);
    d[i] = o;
  }
}
__global__ __launch_bounds__(256) void cvt3(const float4* s0, const float4* s1, const float4* s2,
                                            ushort4* d0, ushort4* d1, ushort4* d2, int n4) {
  const float4* s = blockIdx.y == 0 ? s0 : (blockIdx.y == 1 ? s1 : s2);
  ushort4* d = blockIdx.y == 0 ? d0 : (blockIdx.y == 1 ? d1 : d2);
  cvt_body(s, d, n4);
}
__global__ __launch_bounds__(256) void cvt4(const float4* s0, const float4* s1, const float4* s2,
                                            const float4* s3, ushort4* d0, ushort4* d1,
                                            ushort4* d2, ushort4* d3, int n4) {
  const float4* s = blockIdx.y == 0 ? s0 : (blockIdx.y == 1 ? s1 : (blockIdx.y == 2 ? s2 : s3));
  ushort4* d = blockIdx.y == 0 ? d0 : (blockIdx.y == 1 ? d1 : (blockIdx.y == 2 ? d2 : d3));
  cvt_body(s, d, n4);
}

// ---------- GEMM: C[m][n] = sum_k A[m][k] * B[n][k]  (M=4096, N=1024, K=1024) ----------
template <typename OUT_T>
__global__ __launch_bounds__(256) void gemm_bt(const unsigned short* __restrict__ A,
                                               const unsigned short* __restrict__ Bw,
                                               OUT_T* __restrict__ C) {
  __shared__ char sA[2][8192];  // [128][32] bf16
  __shared__ char sB[2][4096];  // [64][32] bf16
  const int tid = threadIdx.x;
  const int w = tid >> 6, lane = tid & 63;
  const int bm = blockIdx.y, bn = blockIdx.x;
  const int wm = w >> 1, wn = w & 1;

  f32x4 acc[4][2];
#pragma unroll
  for (int i = 0; i < 4; ++i)
#pragma unroll
    for (int j = 0; j < 2; ++j) acc[i][j] = (f32x4){0.f, 0.f, 0.f, 0.f};

  const char* aS0 = (const char*)A + ((size_t)(bm * 128 + w * 32 + (lane >> 2)) << 11) + (lane & 3) * 16;
  const char* aS1 = aS0 + (16 << 11);
  const char* bS  = (const char*)Bw + ((size_t)(bn * 64 + w * 16 + (lane >> 2)) << 11) + (lane & 3) * 16;

  const int aRoff = (wm * 64 + (lane & 15)) * 64 + ((lane >> 4) << 4);
  const int bRoff = (wn * 32 + (lane & 15)) * 64 + ((lane >> 4) << 4);

  gload16(aS0, &sA[0][(w * 2 + 0) * 1024]);
  gload16(aS1, &sA[0][(w * 2 + 1) * 1024]);
  gload16(bS, &sB[0][w * 1024]);
  aS0 += 64; aS1 += 64; bS += 64;

  for (int kt = 0; kt < 32; ++kt) {
    const int cur = kt & 1;
    __syncthreads();
    if (kt < 31) {
      gload16(aS0, &sA[cur ^ 1][(w * 2 + 0) * 1024]);
      gload16(aS1, &sA[cur ^ 1][(w * 2 + 1) * 1024]);
      gload16(bS, &sB[cur ^ 1][w * 1024]);
      aS0 += 64; aS1 += 64; bS += 64;
    }
    bf16x8 aF[4], bF[2];
#pragma unroll
    for (int mi = 0; mi < 4; ++mi) aF[mi] = *(const bf16x8*)(&sA[cur][aRoff + mi * 16 * 64]);
#pragma unroll
    for (int ni = 0; ni < 2; ++ni) bF[ni] = *(const bf16x8*)(&sB[cur][bRoff + ni * 16 * 64]);
#pragma unroll
    for (int mi = 0; mi < 4; ++mi)
#pragma unroll
      for (int ni = 0; ni < 2; ++ni)
        acc[mi][ni] = __builtin_amdgcn_mfma_f32_16x16x32_bf16(aF[mi], bF[ni], acc[mi][ni], 0, 0, 0);
  }

  const int r0 = bm * 128 + wm * 64 + ((lane >> 4) << 2);
  const int c0 = bn * 64 + wn * 32 + (lane & 15);
#pragma unroll
  for (int mi = 0; mi < 4; ++mi)
#pragma unroll
    for (int ni = 0; ni < 2; ++ni)
#pragma unroll
      for (int i = 0; i < 4; ++i) {
        size_t idx = (size_t)(r0 + mi * 16 + i) * 1024 + (c0 + ni * 16);
        if constexpr (sizeof(OUT_T) == 4)
          C[idx] = acc[mi][ni][i];
        else
          C[idx] = f2bf(acc[mi][ni][i]);
      }
}

// ---------- per-head LayerNorm + packed/swizzled tile layout ----------
__global__ __launch_bounds__(256) void ln_pack(const unsigned short* __restrict__ Y,
                                               unsigned short* __restrict__ P, float oscale) {
  const int tid = threadIdx.x;
  const int rid = blockIdx.x * 32 + (tid >> 3);
  const int sub = tid & 7;
  const uint4 v = *(const uint4*)(Y + (size_t)rid * 64 + sub * 8);
  float x[8];
  x[0] = bf2f((unsigned short)(v.x & 0xffff)); x[1] = bf2f((unsigned short)(v.x >> 16));
  x[2] = bf2f((unsigned short)(v.y & 0xffff)); x[3] = bf2f((unsigned short)(v.y >> 16));
  x[4] = bf2f((unsigned short)(v.z & 0xffff)); x[5] = bf2f((unsigned short)(v.z >> 16));
  x[6] = bf2f((unsigned short)(v.w & 0xffff)); x[7] = bf2f((unsigned short)(v.w >> 16));
  float s = 0.f, ss = 0.f;
#pragma unroll
  for (int j = 0; j < 8; ++j) { s += x[j]; ss += x[j] * x[j]; }
#pragma unroll
  for (int msk = 1; msk <= 4; msk <<= 1) {
    s += __shfl_xor(s, msk);
    ss += __shfl_xor(ss, msk);
  }
  const float mean = s * 0.015625f;
  const float var = ss * 0.015625f - mean * mean;
  const float rstd = rsqrtf(var + 1e-5f) * oscale;
  unsigned o[4];
#pragma unroll
  for (int j = 0; j < 4; ++j) {
    unsigned lo = f2bf((x[2 * j] - mean) * rstd);
    unsigned hi = f2bf((x[2 * j + 1] - mean) * rstd);
    o[j] = lo | (hi << 16);
  }
  const int b = rid >> 15, n = (rid >> 4) & 2047, h = rid & 15;
  const int bh = b * 16 + h, t = n >> 6, r = n & 63;
  char* dst = (char*)P + (((size_t)(bh * 32 + t) * 64 + r) << 7) + ((sub * 16) ^ ((r & 7) << 4));
  *(uint4*)dst = make_uint4(o[0], o[1], o[2], o[3]);
}

// ---------- V transpose + pack:  VT[bh][t][d][n-swizzled] ----------
__global__ __launch_bounds__(256) void vt_pack(const unsigned short* __restrict__ Y,
                                               unsigned short* __restrict__ VT) {
  const int bh = blockIdx.x >> 5, t = blockIdx.x & 31;
  const int b = bh >> 4, h = bh & 15;
  __shared__ unsigned short tile[64][72];
  const int tid = threadIdx.x;
#pragma unroll
  for (int it = 0; it < 2; ++it) {
    const int cid = it * 256 + tid;
    const int nl = cid >> 3, dc = cid & 7;
    const uint4 v = *(const uint4*)(Y + ((size_t)(b * 2048 + t * 64 + nl) * 1024 + h * 64 + dc * 8));
    *(uint4*)&tile[nl][dc * 8] = v;
  }
  __syncthreads();
#pragma unroll
  for (int it = 0; it < 2; ++it) {
    const int cid = it * 256 + tid;
    const int d = cid >> 3, nc = cid & 7;
    unsigned o[4];
#pragma unroll
    for (int j = 0; j < 4; ++j)
      o[j] = (unsigned)tile[nc * 8 + 2 * j][d] | ((unsigned)tile[nc * 8 + 2 * j + 1][d] << 16);
    char* dst = (char*)VT + (((size_t)(bh * 32 + t) * 64 + d) << 7) + ((nc * 16) ^ ((d & 7) << 4));
    *(uint4*)dst = make_uint4(o[0], o[1], o[2], o[3]);
  }
}

// ---------- flash attention, swapped-operand 32x32, in-register softmax ----------
// grid (16 qt, 32 bh, 2 half), 256 threads = 4 waves x 32 q-rows. KV half = 1024.
__global__ __launch_bounds__(256, 4) void attn_fused(
    const unsigned short* __restrict__ Qp, const unsigned short* __restrict__ Kp,
    const unsigned short* __restrict__ Vp, unsigned short* __restrict__ Opart,
    float2* __restrict__ ML) {
  const int qt = blockIdx.x, bh = blockIdx.y, half = blockIdx.z;
  __shared__ char sK[2][8192];  // K tile [64 k][64 d], swizzled 128B rows
  __shared__ char sV[2][8192];  // V^T tile [64 d][64 k], swizzled
  const int tid = threadIdx.x, w = tid >> 6, lane = tid & 63;
  const int q5 = lane & 31, hi = lane >> 5;

  const char* qg = (const char*)Qp + ((size_t)bh * 32 + qt * 2) * 8192;
  const char* kg = (const char*)Kp + ((size_t)bh * 32 + half * 16) * 8192;
  const char* vg = (const char*)Vp + ((size_t)bh * 32 + half * 16) * 8192;

  // stage Q (16 KB) into sK region, pull B-frags to regs, then free it
#pragma unroll
  for (int t = 0; t < 4; ++t)
    gload16(qg + (w * 4 + t) * 1024 + lane * 16, (char*)sK + (w * 4 + t) * 1024);
  __syncthreads();
  bf16x8 qf[4];
  {
    const int r128 = w * 32 + q5, tt = r128 >> 6, r = r128 & 63;
#pragma unroll
    for (int dc = 0; dc < 4; ++dc) {
      const int cb = dc * 32 + hi * 16;
      qf[dc] = *(const bf16x8*)((const char*)sK + tt * 8192 + r * 128 + (cb ^ ((r & 7) << 4)));
    }
  }
  __syncthreads();

  // stage KV tile 0
#pragma unroll
  for (int t = 0; t < 2; ++t) {
    gload16(kg + (w * 2 + t) * 1024 + lane * 16, &sK[0][(w * 2 + t) * 1024]);
    gload16(vg + (w * 2 + t) * 1024 + lane * 16, &sV[0][(w * 2 + t) * 1024]);
  }

  f32x16 o0 = {0,0,0,0,0,0,0,0,0,0,0,0,0,0,0,0};
  f32x16 o1 = {0,0,0,0,0,0,0,0,0,0,0,0,0,0,0,0};
  float m = -1e30f, l = 0.f;

  for (int kt = 0; kt < 16; ++kt) {
    const int cur = kt & 1;
    __syncthreads();
    if (kt < 15) {
#pragma unroll
      for (int t = 0; t < 2; ++t) {
        gload16(kg + (size_t)(kt + 1) * 8192 + (w * 2 + t) * 1024 + lane * 16,
                &sK[cur ^ 1][(w * 2 + t) * 1024]);
        gload16(vg + (size_t)(kt + 1) * 8192 + (w * 2 + t) * 1024 + lane * 16,
                &sV[cur ^ 1][(w * 2 + t) * 1024]);
      }
    }
    // S^T = K * Q^T : lane holds S[q5][k] for 32 k (interleaved)
    f32x16 s0 = {0,0,0,0,0,0,0,0,0,0,0,0,0,0,0,0};
    f32x16 s1 = {0,0,0,0,0,0,0,0,0,0,0,0,0,0,0,0};
#pragma unroll
    for (int dc = 0; dc < 4; ++dc) {
      const int cb = dc * 32 + hi * 16;
      const int ra = q5, rb = 32 + q5;
      bf16x8 kf0 = *(const bf16x8*)(&sK[cur][ra * 128 + (cb ^ ((ra & 7) << 4))]);
      bf16x8 kf1 = *(const bf16x8*)(&sK[cur][rb * 128 + (cb ^ ((rb & 7) << 4))]);
      s0 = __builtin_amdgcn_mfma_f32_32x32x16_bf16(kf0, qf[dc], s0, 0, 0, 0);
      s1 = __builtin_amdgcn_mfma_f32_32x32x16_bf16(kf1, qf[dc], s1, 0, 0, 0);
    }
    // lane-local row max (tree) + cross-half swap
    float t16[16];
#pragma unroll
    for (int r = 0; r < 16; ++r) t16[r] = fmaxf(s0[r], s1[r]);
#pragma unroll
    for (int st = 8; st > 0; st >>= 1)
#pragma unroll
      for (int r = 0; r < st; ++r) t16[r] = fmaxf(t16[r], t16[r + st]);
    const float mx = fmaxf(t16[0], __shfl_xor(t16[0], 32));
    // defer-max (THR=8): rescale only when the running max grows materially
    if (__any(mx > m + 8.f)) {
      const float mn = fmaxf(m, mx);
      const float corr = exp2f((m - mn) * L2E);
      l *= corr;
#pragma unroll
      for (int r = 0; r < 16; ++r) { o0[r] *= corr; o1[r] *= corr; }
      m = mn;
    }
    const float nmL2 = -m * L2E;
    unsigned pk[4][4];
    float rs = 0.f;
#define DO_CHUNK(c, SV, B)                                              \
  {                                                                     \
    float p0 = exp2f(fmaf(SV[B + 0], L2E, nmL2));                       \
    float p1 = exp2f(fmaf(SV[B + 1], L2E, nmL2));                       \
    float p2 = exp2f(fmaf(SV[B + 2], L2E, nmL2));                       \
    float p3 = exp2f(fmaf(SV[B + 3], L2E, nmL2));                       \
    float p4 = exp2f(fmaf(SV[B + 4], L2E, nmL2));                       \
    float p5 = exp2f(fmaf(SV[B + 5], L2E, nmL2));                       \
    float p6 = exp2f(fmaf(SV[B + 6], L2E, nmL2));                       \
    float p7 = exp2f(fmaf(SV[B + 7], L2E, nmL2));                       \
    rs += ((p0 + p1) + (p2 + p3)) + ((p4 + p5) + (p6 + p7));            \
    unsigned a0 = cvtpk2(p0, p1), a1 = cvtpk2(p2, p3);                  \
    unsigned b0 = cvtpk2(p4, p5), b1 = cvtpk2(p6, p7);                  \
    plswap(a0, b0);                                                     \
    plswap(a1, b1);                                                     \
    pk[c][0] = a0; pk[c][1] = a1; pk[c][2] = b0; pk[c][3] = b1;         \
  }
    DO_CHUNK(0, s0, 0)
    DO_CHUNK(1, s0, 8)
    DO_CHUNK(2, s1, 0)
    DO_CHUNK(3, s1, 8)
#undef DO_CHUNK
    rs += __shfl_xor(rs, 32);
    l += rs;
    // O^T += V^T * P^T
#pragma unroll
    for (int kk = 0; kk < 4; ++kk) {
      const int cb = kk * 32 + hi * 16;
      const int ra = q5, rb = 32 + q5;
      bf16x8 vf0 = *(const bf16x8*)(&sV[cur][ra * 128 + (cb ^ ((ra & 7) << 4))]);
      bf16x8 vf1 = *(const bf16x8*)(&sV[cur][rb * 128 + (cb ^ ((rb & 7) << 4))]);
      u32x4 pw = {pk[kk][0], pk[kk][1], pk[kk][2], pk[kk][3]};
      bf16x8 pb = __builtin_bit_cast(bf16x8, pw);
      o0 = __builtin_amdgcn_mfma_f32_32x32x16_bf16(vf0, pb, o0, 0, 0, 0);
      o1 = __builtin_amdgcn_mfma_f32_32x32x16_bf16(vf1, pb, o1, 0, 0, 0);
    }
  }

  // epilogue: normalized partial (O/l) bf16 + (m,l)
  const float invl = 1.f / l;
  const int q = qt * 128 + w * 32 + q5;
  unsigned short* ob = Opart + ((size_t)(half * 32 + bh) * 2048 + q) * 64;
#pragma unroll
  for (int g = 0; g < 4; ++g) {
    unsigned d0 = cvtpk2(o0[4 * g + 0] * invl, o0[4 * g + 1] * invl);
    unsigned d1 = cvtpk2(o0[4 * g + 2] * invl, o0[4 * g + 3] * invl);
    *(uint2*)(ob + 8 * g + 4 * hi) = make_uint2(d0, d1);
    unsigned e0 = cvtpk2(o1[4 * g + 0] * invl, o1[4 * g + 1] * invl);
    unsigned e1 = cvtpk2(o1[4 * g + 2] * invl, o1[4 * g + 3] * invl);
    *(uint2*)(ob + 32 + 8 * g + 4 * hi) = make_uint2(e0, e1);
  }
  if (hi == 0) ML[(size_t)(half * 32 + bh) * 2048 + q] = make_float2(m, l);
}

// ---------- merge the two KV-half partials ----------
__global__ __launch_bounds__(256) void attn_merge(const unsigned short* __restrict__ Op,
                                                  const float2* __restrict__ ML,
                                                  unsigned short* __restrict__ O) {
  const int gid = blockIdx.x * 256 + threadIdx.x;  // 524288 = 65536 rows x 8
  const int row = gid >> 3, sub = gid & 7;
  const float2 ml0 = ML[row];
  const float2 ml1 = ML[65536 + row];
  const float mm = fmaxf(ml0.x, ml1.x);
  float w0 = ml0.y * exp2f((ml0.x - mm) * L2E);
  float w1 = ml1.y * exp2f((ml1.x - mm) * L2E);
  const float inv = 1.f / (w0 + w1);
  w0 *= inv; w1 *= inv;
  const uint4 a = *(const uint4*)(Op + (size_t)row * 64 + sub * 8);
  const uint4 b = *(const uint4*)(Op + (size_t)(65536 + row) * 64 + sub * 8);
  const unsigned av[4] = {a.x, a.y, a.z, a.w};
  const unsigned bv[4] = {b.x, b.y, b.z, b.w};
  unsigned ov[4];
#pragma unroll
  for (int j = 0; j < 4; ++j) {
    float r0 = w0 * bf2f((unsigned short)(av[j] & 0xffff)) + w1 * bf2f((unsigned short)(bv[j] & 0xffff));
    float r1 = w0 * bf2f((unsigned short)(av[j] >> 16)) + w1 * bf2f((unsigned short)(bv[j] >> 16));
    ov[j] = (unsigned)f2bf(r0) | ((unsigned)f2bf(r1) << 16);
  }
  const int bh = row >> 11, q = row & 2047, bb = bh >> 4, h = bh & 15;
  *(uint4*)(O + ((size_t)(bb * 2048 + q) * 1024 + h * 64 + sub * 8)) =
      make_uint4(ov[0], ov[1], ov[2], ov[3]);
}

// ---------- launch ----------
extern "C" void kernel_launch(void* const* d_in, const int* in_sizes, int n_in,
                              void* d_out, int out_size, void* d_ws, size_t ws_size,
                              hipStream_t stream) {
  const float* xq = (const float*)d_in[0];
  const float* xk = (const float*)d_in[1];
  const float* xv = (const float*)d_in[2];
  const float* wq = (const float*)d_in[3];
  const float* wk = (const float*)d_in[4];
  const float* wv = (const float*)d_in[5];
  const float* wp = (const float*)d_in[6];

  const size_t NX = 4194304;  // B*N*D
  const size_t NW = 1048576;  // D*D
  unsigned short* base = (unsigned short*)d_ws;
  unsigned short* xqb = base;
  unsigned short* xkb = xqb + NX;
  unsigned short* xvb = xkb + NX;
  unsigned short* wqb = xvb + NX;
  unsigned short* wkb = wqb + NW;
  unsigned short* wvb = wkb + NW;
  unsigned short* wpb = wvb + NW;
  unsigned short* ybuf = wpb + NW;
  unsigned short* qh = ybuf + NX;
  unsigned short* kh = qh + NX;
  unsigned short* vt = kh + NX;
  unsigned short* obf = vt + NX;
  // attn partials alias the x-input bf16 buffers (dead after the 3 projections)
  unsigned short* opart = base;               // 2*NX ushorts
  float2* ml = (float2*)(base + 2 * NX);      // 1 MB inside xvb region

  cvt3<<<dim3(512, 3), 256, 0, stream>>>((const float4*)xq, (const float4*)xk, (const float4*)xv,
                                         (ushort4*)xqb, (ushort4*)xkb, (ushort4*)xvb, (int)(NX / 4));
  cvt4<<<dim3(256, 4), 256, 0, stream>>>((const float4*)wq, (const float4*)wk, (const float4*)wv,
                                         (const float4*)wp, (ushort4*)wqb, (ushort4*)wkb,
                                         (ushort4*)wvb, (ushort4*)wpb, (int)(NW / 4));

  const dim3 gg(16, 32);  // (N/64, M/128)
  gemm_bt<unsigned short><<<gg, 256, 0, stream>>>(xqb, wqb, ybuf);
  ln_pack<<<2048, 256, 0, stream>>>(ybuf, qh, 0.125f);
  gemm_bt<unsigned short><<<gg, 256, 0, stream>>>(xkb, wkb, ybuf);
  ln_pack<<<2048, 256, 0, stream>>>(ybuf, kh, 1.0f);
  gemm_bt<unsigned short><<<gg, 256, 0, stream>>>(xvb, wvb, ybuf);
  vt_pack<<<1024, 256, 0, stream>>>(ybuf, vt);

  attn_fused<<<dim3(16, 32, 2), 256, 0, stream>>>(qh, kh, vt, opart, ml);
  attn_merge<<<2048, 256, 0, stream>>>(opart, ml, obf);

  gemm_bt<float><<<gg, 256, 0, stream>>>(obf, wpb, (float*)d_out);
}

// Round 3
// 141.977 us; speedup vs baseline: 1.8232x; 1.3891x over previous
//
#include <hip/hip_runtime.h>

typedef __bf16 bf16x8 __attribute__((ext_vector_type(8)));
typedef float f32x4 __attribute__((ext_vector_type(4)));
typedef float f32x16 __attribute__((ext_vector_type(16)));
typedef unsigned u32x4 __attribute__((ext_vector_type(4)));

#define DEV __device__ __forceinline__
#define L2E 1.44269504f

// ---------- helpers ----------
DEV unsigned short f2bf(float f) {  // round-to-nearest-even f32 -> bf16
  unsigned u = __float_as_uint(f);
  u += 0x7fffu + ((u >> 16) & 1u);
  return (unsigned short)(u >> 16);
}
DEV float bf2f(unsigned short h) { return __uint_as_float(((unsigned)h) << 16); }

DEV void gload16(const void* g, void* l) {
  // async global->LDS; LDS dest must be wave-uniform (HW adds lane*16)
  __builtin_amdgcn_global_load_lds((const __attribute__((address_space(1))) void*)g,
                                   (__attribute__((address_space(3))) void*)l, 16, 0, 0);
}

DEV unsigned cvtpk2(float lo, float hi) {  // dword = {bf16(lo), bf16(hi)<<16}
  unsigned r;
  asm("v_cvt_pk_bf16_f32 %0, %1, %2" : "=v"(r) : "v"(lo), "v"(hi));
  return r;
}
DEV void plswap(unsigned& a, unsigned& b) {  // a.hi_lanes <-> b.lo_lanes
  asm volatile("v_permlane32_swap_b32 %0, %1" : "+v"(a), "+v"(b));
}
DEV float ex2(float x) {  // 2^x, single v_exp_f32 (libm exp2f is ~25 instrs w/o fast-math)
  float r;
  asm("v_exp_f32 %0, %1" : "=v"(r) : "v"(x));
  return r;
}

// ---------- fp32 -> bf16 converts (consolidated) ----------
DEV void cvt_body(const float4* __restrict__ s, ushort4* __restrict__ d, int n4) {
  for (int i = blockIdx.x * 256 + threadIdx.x; i < n4; i += gridDim.x * 256) {
    float4 v = s[i];
    ushort4 o;
    o.x = f2bf(v.x); o.y = f2bf(v.y); o.z = f2bf(v.z); o.w = f2bf(v.w);
    d[i] = o;
  }
}
__global__ __launch_bounds__(256) void cvt3(const float4* s0, const float4* s1, const float4* s2,
                                            ushort4* d0, ushort4* d1, ushort4* d2, int n4) {
  const float4* s = blockIdx.y == 0 ? s0 : (blockIdx.y == 1 ? s1 : s2);
  ushort4* d = blockIdx.y == 0 ? d0 : (blockIdx.y == 1 ? d1 : d2);
  cvt_body(s, d, n4);
}
__global__ __launch_bounds__(256) void cvt4(const float4* s0, const float4* s1, const float4* s2,
                                            const float4* s3, ushort4* d0, ushort4* d1,
                                            ushort4* d2, ushort4* d3, int n4) {
  const float4* s = blockIdx.y == 0 ? s0 : (blockIdx.y == 1 ? s1 : (blockIdx.y == 2 ? s2 : s3));
  ushort4* d = blockIdx.y == 0 ? d0 : (blockIdx.y == 1 ? d1 : (blockIdx.y == 2 ? d2 : d3));
  cvt_body(s, d, n4);
}

// ---------- GEMM core: 128x128 tile, BK=64, single-buffer, 2 barriers/step ----------
// C[m][n] = sum_k A[m][k]*W[n][k], M=4096, N=1024, K=1024. 4 waves (2x2), 64x64 each.
// LDS rows are 128B with chunk-XOR swizzle (chunk ^= row&7) applied on the GLOBAL
// source address (linear LDS dest for global_load_lds) and on ds_read -> 2-way max.
DEV void gemm_core(const unsigned short* __restrict__ A, const unsigned short* __restrict__ W,
                   char* sA, char* sB, f32x4 acc[4][4], int bm, int bn, int tid) {
  const int w = tid >> 6, lane = tid & 63;
  const int wm = w >> 1, wn = w & 1;
  // staging: call c covers rows c*32 + w*8 + (lane>>3); chunk_g = (lane&7)^(lane>>3)
  const char* aB = (const char*)A + ((size_t)(bm * 128 + (lane >> 3)) << 11) +
                   (((lane & 7) ^ (lane >> 3)) << 4);
  const char* bB = (const char*)W + ((size_t)(bn * 128 + (lane >> 3)) << 11) +
                   (((lane & 7) ^ (lane >> 3)) << 4);
  const int ldsBase = w * 1024;  // wave-uniform; HW appends lane*16

  for (int kt = 0; kt < 16; ++kt) {
    const int ko = kt * 128;
#pragma unroll
    for (int c = 0; c < 4; ++c) {
      gload16(aB + ((size_t)(c * 32 + w * 8) << 11) + ko, sA + c * 4096 + ldsBase);
      gload16(bB + ((size_t)(c * 32 + w * 8) << 11) + ko, sB + c * 4096 + ldsBase);
    }
    __syncthreads();  // vmcnt(0) drain: tile staged
#pragma unroll
    for (int kk = 0; kk < 2; ++kk) {
      const int ch = ((kk * 4 + (lane >> 4)) ^ (lane & 7)) << 4;
      bf16x8 aF[4], bF[4];
#pragma unroll
      for (int mi = 0; mi < 4; ++mi)
        aF[mi] = *(const bf16x8*)(sA + (wm * 64 + mi * 16 + (lane & 15)) * 128 + ch);
#pragma unroll
      for (int ni = 0; ni < 4; ++ni)
        bF[ni] = *(const bf16x8*)(sB + (wn * 64 + ni * 16 + (lane & 15)) * 128 + ch);
#pragma unroll
      for (int mi = 0; mi < 4; ++mi)
#pragma unroll
        for (int ni = 0; ni < 4; ++ni)
          acc[mi][ni] = __builtin_amdgcn_mfma_f32_16x16x32_bf16(aF[mi], bF[ni], acc[mi][ni], 0, 0, 0);
    }
    __syncthreads();  // all waves done reading before next stage overwrites
  }
}

// Fused QKV projections. z=0: Q -> LN+pack (scale 0.125*L2E), z=1: K -> LN+pack,
// z=2: V -> plain bf16 row-major (vt_pack consumes).
__global__ __launch_bounds__(256, 3) void gemm_qkv(
    const unsigned short* __restrict__ xq, const unsigned short* __restrict__ xk,
    const unsigned short* __restrict__ xv, const unsigned short* __restrict__ wq,
    const unsigned short* __restrict__ wk, const unsigned short* __restrict__ wv,
    unsigned short* __restrict__ qh, unsigned short* __restrict__ kh,
    unsigned short* __restrict__ ybuf) {
  __shared__ char sA[16384], sB[16384];
  const int z = blockIdx.z;
  const unsigned short* A = z == 0 ? xq : (z == 1 ? xk : xv);
  const unsigned short* W = z == 0 ? wq : (z == 1 ? wk : wv);
  f32x4 acc[4][4];
#pragma unroll
  for (int i = 0; i < 4; ++i)
#pragma unroll
    for (int j = 0; j < 4; ++j) acc[i][j] = (f32x4){0.f, 0.f, 0.f, 0.f};

  const int tid = threadIdx.x, bm = blockIdx.y, bn = blockIdx.x;
  gemm_core(A, W, sA, sB, acc, bm, bn, tid);

  const int w = tid >> 6, lane = tid & 63, wm = w >> 1, wn = w & 1;
  if (z == 2) {
    const int r0 = bm * 128 + wm * 64 + ((lane >> 4) << 2);
    const int c0 = bn * 128 + wn * 64 + (lane & 15);
#pragma unroll
    for (int mi = 0; mi < 4; ++mi)
#pragma unroll
      for (int ni = 0; ni < 4; ++ni)
#pragma unroll
        for (int i = 0; i < 4; ++i)
          ybuf[(size_t)(r0 + mi * 16 + i) * 1024 + (c0 + ni * 16)] = f2bf(acc[mi][ni][i]);
  } else {
    unsigned short* dst = z == 0 ? qh : kh;
    const float osc = z == 0 ? 0.125f * L2E : 1.0f;  // fold muP scale + log2(e) into Q
    const int h = bn * 2 + wn;  // wave's 64-col span == one head
#pragma unroll
    for (int mi = 0; mi < 4; ++mi)
#pragma unroll
      for (int i = 0; i < 4; ++i) {
        float s4 = 0.f, ss4 = 0.f;
#pragma unroll
        for (int ni = 0; ni < 4; ++ni) {
          float v = acc[mi][ni][i];
          s4 += v;
          ss4 += v * v;
        }
#pragma unroll
        for (int msk = 1; msk <= 8; msk <<= 1) {
          s4 += __shfl_xor(s4, msk);
          ss4 += __shfl_xor(ss4, msk);
        }
        const float mean = s4 * 0.015625f;
        const float var = ss4 * 0.015625f - mean * mean;
        const float rstd = rsqrtf(var + 1e-5f) * osc;
        const int g = bm * 128 + wm * 64 + mi * 16 + ((lane >> 4) << 2) + i;
        const int b = g >> 11, n = g & 2047;
        const int bh = b * 16 + h, t = n >> 6, rr = n & 63;
        char* rowp = (char*)dst + (((size_t)(bh * 32 + t) * 64 + rr) << 7);
        const int swz = (rr & 7) << 4;
#pragma unroll
        for (int ni = 0; ni < 4; ++ni) {
          const int j2 = (ni * 16 + (lane & 15)) * 2;
          *(unsigned short*)(rowp + (j2 ^ swz)) = f2bf((acc[mi][ni][i] - mean) * rstd);
        }
      }
  }
}

// Final projection: f32 output
__global__ __launch_bounds__(256, 3) void gemm_out(const unsigned short* __restrict__ A,
                                                   const unsigned short* __restrict__ W,
                                                   float* __restrict__ C) {
  __shared__ char sA[16384], sB[16384];
  f32x4 acc[4][4];
#pragma unroll
  for (int i = 0; i < 4; ++i)
#pragma unroll
    for (int j = 0; j < 4; ++j) acc[i][j] = (f32x4){0.f, 0.f, 0.f, 0.f};
  const int tid = threadIdx.x, bm = blockIdx.y, bn = blockIdx.x;
  gemm_core(A, W, sA, sB, acc, bm, bn, tid);
  const int w = tid >> 6, lane = tid & 63, wm = w >> 1, wn = w & 1;
  const int r0 = bm * 128 + wm * 64 + ((lane >> 4) << 2);
  const int c0 = bn * 128 + wn * 64 + (lane & 15);
#pragma unroll
  for (int mi = 0; mi < 4; ++mi)
#pragma unroll
    for (int ni = 0; ni < 4; ++ni)
#pragma unroll
      for (int i = 0; i < 4; ++i)
        C[(size_t)(r0 + mi * 16 + i) * 1024 + (c0 + ni * 16)] = acc[mi][ni][i];
}

// ---------- V transpose + pack:  VT[bh][t][d][n-swizzled] ----------
__global__ __launch_bounds__(256) void vt_pack(const unsigned short* __restrict__ Y,
                                               unsigned short* __restrict__ VT) {
  const int bh = blockIdx.x >> 5, t = blockIdx.x & 31;
  const int b = bh >> 4, h = bh & 15;
  __shared__ unsigned short tile[64][72];
  const int tid = threadIdx.x;
#pragma unroll
  for (int it = 0; it < 2; ++it) {
    const int cid = it * 256 + tid;
    const int nl = cid >> 3, dc = cid & 7;
    const uint4 v = *(const uint4*)(Y + ((size_t)(b * 2048 + t * 64 + nl) * 1024 + h * 64 + dc * 8));
    *(uint4*)&tile[nl][dc * 8] = v;
  }
  __syncthreads();
#pragma unroll
  for (int it = 0; it < 2; ++it) {
    const int cid = it * 256 + tid;
    const int d = cid >> 3, nc = cid & 7;
    unsigned o[4];
#pragma unroll
    for (int j = 0; j < 4; ++j)
      o[j] = (unsigned)tile[nc * 8 + 2 * j][d] | ((unsigned)tile[nc * 8 + 2 * j + 1][d] << 16);
    char* dst = (char*)VT + (((size_t)(bh * 32 + t) * 64 + d) << 7) + ((nc * 16) ^ ((d & 7) << 4));
    *(uint4*)dst = make_uint4(o[0], o[1], o[2], o[3]);
  }
}

// ---------- flash attention, swapped-operand 32x32, in-register softmax ----------
// Scores arrive in log2 domain (L2E folded into Q's LN scale).
__global__ __launch_bounds__(256, 4) void attn_fused(
    const unsigned short* __restrict__ Qp, const unsigned short* __restrict__ Kp,
    const unsigned short* __restrict__ Vp, unsigned short* __restrict__ Opart,
    float2* __restrict__ ML) {
  const int qt = blockIdx.x, bh = blockIdx.y, half = blockIdx.z;
  __shared__ char sK[2][8192];  // K tile [64 k][64 d], swizzled 128B rows
  __shared__ char sV[2][8192];  // V^T tile [64 d][64 k], swizzled
  const int tid = threadIdx.x, w = tid >> 6, lane = tid & 63;
  const int q5 = lane & 31, hi = lane >> 5;

  const char* qg = (const char*)Qp + ((size_t)bh * 32 + qt * 2) * 8192;
  const char* kg = (const char*)Kp + ((size_t)bh * 32 + half * 16) * 8192;
  const char* vg = (const char*)Vp + ((size_t)bh * 32 + half * 16) * 8192;

#pragma unroll
  for (int t = 0; t < 4; ++t)
    gload16(qg + (w * 4 + t) * 1024 + lane * 16, (char*)sK + (w * 4 + t) * 1024);
  __syncthreads();
  bf16x8 qf[4];
  {
    const int r128 = w * 32 + q5, tt = r128 >> 6, r = r128 & 63;
#pragma unroll
    for (int dc = 0; dc < 4; ++dc) {
      const int cb = dc * 32 + hi * 16;
      qf[dc] = *(const bf16x8*)((const char*)sK + tt * 8192 + r * 128 + (cb ^ ((r & 7) << 4)));
    }
  }
  __syncthreads();

#pragma unroll
  for (int t = 0; t < 2; ++t) {
    gload16(kg + (w * 2 + t) * 1024 + lane * 16, &sK[0][(w * 2 + t) * 1024]);
    gload16(vg + (w * 2 + t) * 1024 + lane * 16, &sV[0][(w * 2 + t) * 1024]);
  }

  f32x16 o0 = {0,0,0,0,0,0,0,0,0,0,0,0,0,0,0,0};
  f32x16 o1 = {0,0,0,0,0,0,0,0,0,0,0,0,0,0,0,0};
  float m = -1e30f, l = 0.f;

  for (int kt = 0; kt < 16; ++kt) {
    const int cur = kt & 1;
    __syncthreads();
    if (kt < 15) {
#pragma unroll
      for (int t = 0; t < 2; ++t) {
        gload16(kg + (size_t)(kt + 1) * 8192 + (w * 2 + t) * 1024 + lane * 16,
                &sK[cur ^ 1][(w * 2 + t) * 1024]);
        gload16(vg + (size_t)(kt + 1) * 8192 + (w * 2 + t) * 1024 + lane * 16,
                &sV[cur ^ 1][(w * 2 + t) * 1024]);
      }
    }
    // S^T = K * Q^T : lane holds S[q5][k] for 32 k
    f32x16 s0 = {0,0,0,0,0,0,0,0,0,0,0,0,0,0,0,0};
    f32x16 s1 = {0,0,0,0,0,0,0,0,0,0,0,0,0,0,0,0};
    __builtin_amdgcn_s_setprio(1);
#pragma unroll
    for (int dc = 0; dc < 4; ++dc) {
      const int cb = dc * 32 + hi * 16;
      const int ra = q5, rb = 32 + q5;
      bf16x8 kf0 = *(const bf16x8*)(&sK[cur][ra * 128 + (cb ^ ((ra & 7) << 4))]);
      bf16x8 kf1 = *(const bf16x8*)(&sK[cur][rb * 128 + (cb ^ ((rb & 7) << 4))]);
      s0 = __builtin_amdgcn_mfma_f32_32x32x16_bf16(kf0, qf[dc], s0, 0, 0, 0);
      s1 = __builtin_amdgcn_mfma_f32_32x32x16_bf16(kf1, qf[dc], s1, 0, 0, 0);
    }
    __builtin_amdgcn_s_setprio(0);
    // lane-local row max + cross-half swap
    float t16[16];
#pragma unroll
    for (int r = 0; r < 16; ++r) t16[r] = fmaxf(s0[r], s1[r]);
#pragma unroll
    for (int st = 8; st > 0; st >>= 1)
#pragma unroll
      for (int r = 0; r < st; ++r) t16[r] = fmaxf(t16[r], t16[r + st]);
    const float mx = fmaxf(t16[0], __shfl_xor(t16[0], 32));
    if (__any(mx > m + 8.f)) {  // defer-max (log2 units)
      const float mn = fmaxf(m, mx);
      const float corr = ex2(m - mn);
      l *= corr;
#pragma unroll
      for (int r = 0; r < 16; ++r) { o0[r] *= corr; o1[r] *= corr; }
      m = mn;
    }
    const float nm = -m;
    unsigned pk[4][4];
    float rs = 0.f;
#define DO_CHUNK(c, SV, B)                                      \
  {                                                             \
    float p0 = ex2(SV[B + 0] + nm);                             \
    float p1 = ex2(SV[B + 1] + nm);                             \
    float p2 = ex2(SV[B + 2] + nm);                             \
    float p3 = ex2(SV[B + 3] + nm);                             \
    float p4 = ex2(SV[B + 4] + nm);                             \
    float p5 = ex2(SV[B + 5] + nm);                             \
    float p6 = ex2(SV[B + 6] + nm);                             \
    float p7 = ex2(SV[B + 7] + nm);                             \
    rs += ((p0 + p1) + (p2 + p3)) + ((p4 + p5) + (p6 + p7));    \
    unsigned a0 = cvtpk2(p0, p1), a1 = cvtpk2(p2, p3);          \
    unsigned b0 = cvtpk2(p4, p5), b1 = cvtpk2(p6, p7);          \
    plswap(a0, b0);                                             \
    plswap(a1, b1);                                             \
    pk[c][0] = a0; pk[c][1] = a1; pk[c][2] = b0; pk[c][3] = b1; \
  }
    DO_CHUNK(0, s0, 0)
    DO_CHUNK(1, s0, 8)
    DO_CHUNK(2, s1, 0)
    DO_CHUNK(3, s1, 8)
#undef DO_CHUNK
    rs += __shfl_xor(rs, 32);
    l += rs;
    // O^T += V^T * P^T
    __builtin_amdgcn_s_setprio(1);
#pragma unroll
    for (int kk = 0; kk < 4; ++kk) {
      const int cb = kk * 32 + hi * 16;
      const int ra = q5, rb = 32 + q5;
      bf16x8 vf0 = *(const bf16x8*)(&sV[cur][ra * 128 + (cb ^ ((ra & 7) << 4))]);
      bf16x8 vf1 = *(const bf16x8*)(&sV[cur][rb * 128 + (cb ^ ((rb & 7) << 4))]);
      u32x4 pw = {pk[kk][0], pk[kk][1], pk[kk][2], pk[kk][3]};
      bf16x8 pb = __builtin_bit_cast(bf16x8, pw);
      o0 = __builtin_amdgcn_mfma_f32_32x32x16_bf16(vf0, pb, o0, 0, 0, 0);
      o1 = __builtin_amdgcn_mfma_f32_32x32x16_bf16(vf1, pb, o1, 0, 0, 0);
    }
    __builtin_amdgcn_s_setprio(0);
  }

  const float invl = 1.f / l;
  const int q = qt * 128 + w * 32 + q5;
  unsigned short* ob = Opart + ((size_t)(half * 32 + bh) * 2048 + q) * 64;
#pragma unroll
  for (int g = 0; g < 4; ++g) {
    unsigned d0 = cvtpk2(o0[4 * g + 0] * invl, o0[4 * g + 1] * invl);
    unsigned d1 = cvtpk2(o0[4 * g + 2] * invl, o0[4 * g + 3] * invl);
    *(uint2*)(ob + 8 * g + 4 * hi) = make_uint2(d0, d1);
    unsigned e0 = cvtpk2(o1[4 * g + 0] * invl, o1[4 * g + 1] * invl);
    unsigned e1 = cvtpk2(o1[4 * g + 2] * invl, o1[4 * g + 3] * invl);
    *(uint2*)(ob + 32 + 8 * g + 4 * hi) = make_uint2(e0, e1);
  }
  if (hi == 0) ML[(size_t)(half * 32 + bh) * 2048 + q] = make_float2(m, l);
}

// ---------- merge the two KV-half partials ----------
__global__ __launch_bounds__(256) void attn_merge(const unsigned short* __restrict__ Op,
                                                  const float2* __restrict__ ML,
                                                  unsigned short* __restrict__ O) {
  const int gid = blockIdx.x * 256 + threadIdx.x;
  const int row = gid >> 3, sub = gid & 7;
  const float2 ml0 = ML[row];
  const float2 ml1 = ML[65536 + row];
  const float mm = fmaxf(ml0.x, ml1.x);
  float w0 = ml0.y * ex2(ml0.x - mm);
  float w1 = ml1.y * ex2(ml1.x - mm);
  const float inv = 1.f / (w0 + w1);
  w0 *= inv; w1 *= inv;
  const uint4 a = *(const uint4*)(Op + (size_t)row * 64 + sub * 8);
  const uint4 b = *(const uint4*)(Op + (size_t)(65536 + row) * 64 + sub * 8);
  const unsigned av[4] = {a.x, a.y, a.z, a.w};
  const unsigned bv[4] = {b.x, b.y, b.z, b.w};
  unsigned ov[4];
#pragma unroll
  for (int j = 0; j < 4; ++j) {
    float r0 = w0 * bf2f((unsigned short)(av[j] & 0xffff)) + w1 * bf2f((unsigned short)(bv[j] & 0xffff));
    float r1 = w0 * bf2f((unsigned short)(av[j] >> 16)) + w1 * bf2f((unsigned short)(bv[j] >> 16));
    ov[j] = (unsigned)f2bf(r0) | ((unsigned)f2bf(r1) << 16);
  }
  const int bh = row >> 11, q = row & 2047, bb = bh >> 4, h = bh & 15;
  *(uint4*)(O + ((size_t)(bb * 2048 + q) * 1024 + h * 64 + sub * 8)) =
      make_uint4(ov[0], ov[1], ov[2], ov[3]);
}

// ---------- launch ----------
extern "C" void kernel_launch(void* const* d_in, const int* in_sizes, int n_in,
                              void* d_out, int out_size, void* d_ws, size_t ws_size,
                              hipStream_t stream) {
  const float* xq = (const float*)d_in[0];
  const float* xk = (const float*)d_in[1];
  const float* xv = (const float*)d_in[2];
  const float* wq = (const float*)d_in[3];
  const float* wk = (const float*)d_in[4];
  const float* wv = (const float*)d_in[5];
  const float* wp = (const float*)d_in[6];

  const size_t NX = 4194304;  // B*N*D
  const size_t NW = 1048576;  // D*D
  unsigned short* base = (unsigned short*)d_ws;
  unsigned short* xqb = base;
  unsigned short* xkb = xqb + NX;
  unsigned short* xvb = xkb + NX;
  unsigned short* wqb = xvb + NX;
  unsigned short* wkb = wqb + NW;
  unsigned short* wvb = wkb + NW;
  unsigned short* wpb = wvb + NW;
  unsigned short* ybuf = wpb + NW;  // V projection only
  unsigned short* qh = ybuf + NX;
  unsigned short* kh = qh + NX;
  unsigned short* vt = kh + NX;
  unsigned short* obf = vt + NX;
  // attn partials alias the x-input bf16 buffers (dead after the projections)
  unsigned short* opart = base;            // 2*NX ushorts
  float2* ml = (float2*)(base + 2 * NX);   // 1 MB inside xvb region

  cvt3<<<dim3(512, 3), 256, 0, stream>>>((const float4*)xq, (const float4*)xk, (const float4*)xv,
                                         (ushort4*)xqb, (ushort4*)xkb, (ushort4*)xvb, (int)(NX / 4));
  cvt4<<<dim3(256, 4), 256, 0, stream>>>((const float4*)wq, (const float4*)wk, (const float4*)wv,
                                         (const float4*)wp, (ushort4*)wqb, (ushort4*)wkb,
                                         (ushort4*)wvb, (ushort4*)wpb, (int)(NW / 4));

  gemm_qkv<<<dim3(8, 32, 3), 256, 0, stream>>>(xqb, xkb, xvb, wqb, wkb, wvb, qh, kh, ybuf);
  vt_pack<<<1024, 256, 0, stream>>>(ybuf, vt);

  attn_fused<<<dim3(16, 32, 2), 256, 0, stream>>>(qh, kh, vt, opart, ml);
  attn_merge<<<2048, 256, 0, stream>>>(opart, ml, obf);

  gemm_out<<<dim3(8, 32), 256, 0, stream>>>(obf, wpb, (float*)d_out);
}

// Round 4
// 129.138 us; speedup vs baseline: 2.0045x; 1.0994x over previous
//
#include <hip/hip_runtime.h>

typedef __bf16 bf16x8 __attribute__((ext_vector_type(8)));
typedef float f32x4 __attribute__((ext_vector_type(4)));
typedef float f32x16 __attribute__((ext_vector_type(16)));
typedef unsigned u32x4 __attribute__((ext_vector_type(4)));

#define DEV __device__ __forceinline__
#define L2E 1.44269504f

// ---------- helpers ----------
DEV unsigned short f2bf(float f) {  // round-to-nearest-even f32 -> bf16
  unsigned u = __float_as_uint(f);
  u += 0x7fffu + ((u >> 16) & 1u);
  return (unsigned short)(u >> 16);
}
DEV float bf2f(unsigned short h) { return __uint_as_float(((unsigned)h) << 16); }

DEV void gload16(const void* g, void* l) {
  // async global->LDS; LDS dest must be wave-uniform (HW adds lane*16)
  __builtin_amdgcn_global_load_lds((const __attribute__((address_space(1))) void*)g,
                                   (__attribute__((address_space(3))) void*)l, 16, 0, 0);
}

DEV unsigned cvtpk2(float lo, float hi) {  // dword = {bf16(lo), bf16(hi)<<16}
  unsigned r;
  asm("v_cvt_pk_bf16_f32 %0, %1, %2" : "=v"(r) : "v"(lo), "v"(hi));
  return r;
}
DEV void plswap(unsigned& a, unsigned& b) {  // a.hi_lanes <-> b.lo_lanes
  asm volatile("v_permlane32_swap_b32 %0, %1" : "+v"(a), "+v"(b));
}
DEV float ex2(float x) {  // 2^x, single v_exp_f32
  float r;
  asm("v_exp_f32 %0, %1" : "=v"(r) : "v"(x));
  return r;
}
DEV float max3(float a, float b, float c) {
  float r;
  asm("v_max3_f32 %0, %1, %2, %3" : "=v"(r) : "v"(a), "v"(b), "v"(c));
  return r;
}

// ---------- fp32 -> bf16 converts (single dispatch) ----------
__global__ __launch_bounds__(256) void cvt7(const float* xq, const float* xk, const float* xv,
                                            const float* wq, const float* wk, const float* wv,
                                            const float* wp, ushort4* xqb, ushort4* xkb,
                                            ushort4* xvb, ushort4* wqb, ushort4* wkb,
                                            ushort4* wvb, ushort4* wpb, int nx4, int nw4) {
  const int y = blockIdx.y;
  const float4* s;
  ushort4* d;
  int n;
  switch (y) {
    case 0: s = (const float4*)xq; d = xqb; n = nx4; break;
    case 1: s = (const float4*)xk; d = xkb; n = nx4; break;
    case 2: s = (const float4*)xv; d = xvb; n = nx4; break;
    case 3: s = (const float4*)wq; d = wqb; n = nw4; break;
    case 4: s = (const float4*)wk; d = wkb; n = nw4; break;
    case 5: s = (const float4*)wv; d = wvb; n = nw4; break;
    default: s = (const float4*)wp; d = wpb; n = nw4; break;
  }
  for (int i = blockIdx.x * 256 + threadIdx.x; i < n; i += gridDim.x * 256) {
    float4 v = s[i];
    ushort4 o;
    o.x = f2bf(v.x); o.y = f2bf(v.y); o.z = f2bf(v.z); o.w = f2bf(v.w);
    d[i] = o;
  }
}

// ---------- GEMM core: 128x128 tile, BK=64, single-buffer, 2 barriers/step ----------
// SWAP=false: acc[mi][ni] holds C[m=mi*16+(lane>>4)*4+reg][n=ni*16+(lane&15)]
// SWAP=true (mfma(bF,aF)): acc holds C[m=mi*16+(lane&15)][n=ni*16+(lane>>4)*4+reg]
template <bool SWAP>
DEV void gemm_core(const unsigned short* __restrict__ A, const unsigned short* __restrict__ W,
                   char* sA, char* sB, f32x4 acc[4][4], int bm, int bn, int tid) {
  const int w = tid >> 6, lane = tid & 63;
  const int wm = w >> 1, wn = w & 1;
  const char* aB = (const char*)A + ((size_t)(bm * 128 + (lane >> 3)) << 11) +
                   (((lane & 7) ^ (lane >> 3)) << 4);
  const char* bB = (const char*)W + ((size_t)(bn * 128 + (lane >> 3)) << 11) +
                   (((lane & 7) ^ (lane >> 3)) << 4);
  const int ldsBase = w * 1024;

  for (int kt = 0; kt < 16; ++kt) {
    const int ko = kt * 128;
#pragma unroll
    for (int c = 0; c < 4; ++c) {
      gload16(aB + ((size_t)(c * 32 + w * 8) << 11) + ko, sA + c * 4096 + ldsBase);
      gload16(bB + ((size_t)(c * 32 + w * 8) << 11) + ko, sB + c * 4096 + ldsBase);
    }
    __syncthreads();
#pragma unroll
    for (int kk = 0; kk < 2; ++kk) {
      const int ch = ((kk * 4 + (lane >> 4)) ^ (lane & 7)) << 4;
      bf16x8 aF[4], bF[4];
#pragma unroll
      for (int mi = 0; mi < 4; ++mi)
        aF[mi] = *(const bf16x8*)(sA + (wm * 64 + mi * 16 + (lane & 15)) * 128 + ch);
#pragma unroll
      for (int ni = 0; ni < 4; ++ni)
        bF[ni] = *(const bf16x8*)(sB + (wn * 64 + ni * 16 + (lane & 15)) * 128 + ch);
#pragma unroll
      for (int mi = 0; mi < 4; ++mi)
#pragma unroll
        for (int ni = 0; ni < 4; ++ni)
          acc[mi][ni] = SWAP ? __builtin_amdgcn_mfma_f32_16x16x32_bf16(bF[ni], aF[mi],
                                                                       acc[mi][ni], 0, 0, 0)
                             : __builtin_amdgcn_mfma_f32_16x16x32_bf16(aF[mi], bF[ni],
                                                                       acc[mi][ni], 0, 0, 0);
    }
    __syncthreads();
  }
}

// Fused QKV projections. z=0: Q -> LN+pack (scale 0.125*L2E), z=1: K -> LN+pack,
// z=2: V -> VT packed layout directly.
__global__ __launch_bounds__(256, 3) void gemm_qkv(
    const unsigned short* __restrict__ xq, const unsigned short* __restrict__ xk,
    const unsigned short* __restrict__ xv, const unsigned short* __restrict__ wq,
    const unsigned short* __restrict__ wk, const unsigned short* __restrict__ wv,
    unsigned short* __restrict__ qh, unsigned short* __restrict__ kh,
    unsigned short* __restrict__ vt) {
  __shared__ char sA[16384], sB[16384];
  const int z = blockIdx.z;
  // XCD swizzle: all 8 bn-blocks of one bm land on one XCD -> A-panel L2 reuse
  const int flat = blockIdx.x + (blockIdx.y << 3);
  const int xcd = flat & 7, ii = flat >> 3;
  const int bm = xcd * 4 + (ii >> 3), bn = ii & 7;
  const int tid = threadIdx.x, w = tid >> 6, lane = tid & 63;
  const int wm = w >> 1, wn = w & 1;

  if (z == 2) {
    f32x4 acc[4][4];
#pragma unroll
    for (int i = 0; i < 4; ++i)
#pragma unroll
      for (int j = 0; j < 4; ++j) acc[i][j] = (f32x4){0.f, 0.f, 0.f, 0.f};
    gemm_core<false>(xv, wv, sA, sB, acc, bm, bn, tid);
    // VT[bh][t][d][n-swz]: normal acc gives 4 consecutive seq rows per (mi,ni)
    const int hb = bn * 2 + wn;
    const int d = (lane & 15);  // + ni*16
    const int g0 = bm * 128 + wm * 64 + ((lane >> 4) << 2);  // + mi*16
#pragma unroll
    for (int mi = 0; mi < 4; ++mi) {
      const int g = g0 + mi * 16;
      const int b = g >> 11, n0 = g & 2047, tq = n0 >> 6, nn = n0 & 63;
#pragma unroll
      for (int ni = 0; ni < 4; ++ni) {
        const int dd = d + ni * 16;
        char* dst = (char*)vt + (((size_t)((b * 16 + hb) * 32 + tq) * 64 + dd) << 7) +
                    ((nn * 2) ^ ((dd & 7) << 4));
        *(uint2*)dst = make_uint2(cvtpk2(acc[mi][ni][0], acc[mi][ni][1]),
                                  cvtpk2(acc[mi][ni][2], acc[mi][ni][3]));
      }
    }
  } else {
    const unsigned short* A = z == 0 ? xq : xk;
    const unsigned short* W = z == 0 ? wq : wk;
    f32x4 acc[4][4];
#pragma unroll
    for (int i = 0; i < 4; ++i)
#pragma unroll
      for (int j = 0; j < 4; ++j) acc[i][j] = (f32x4){0.f, 0.f, 0.f, 0.f};
    gemm_core<true>(A, W, sA, sB, acc, bm, bn, tid);
    // LN over d (lane holds 16 of 64 d's for ONE row per mi; partners lane^16, lane^32)
    unsigned short* dst = z == 0 ? qh : kh;
    const float osc = z == 0 ? 0.125f * L2E : 1.0f;  // fold muP scale + log2(e) into Q
    const int h = bn * 2 + wn;
    const int d0b = (lane >> 4) << 3;
#pragma unroll
    for (int mi = 0; mi < 4; ++mi) {
      float s = 0.f, ss = 0.f;
#pragma unroll
      for (int ni = 0; ni < 4; ++ni)
#pragma unroll
        for (int r = 0; r < 4; ++r) {
          const float v = acc[mi][ni][r];
          s += v;
          ss += v * v;
        }
      s += __shfl_xor(s, 16); ss += __shfl_xor(ss, 16);
      s += __shfl_xor(s, 32); ss += __shfl_xor(ss, 32);
      const float mean = s * 0.015625f;
      const float var = ss * 0.015625f - mean * mean;
      const float rstd = rsqrtf(var + 1e-5f) * osc;
      const float mr = mean * rstd;
      const int g = bm * 128 + wm * 64 + mi * 16 + (lane & 15);
      const int b = g >> 11, n = g & 2047;
      const int bh = b * 16 + h, tq = n >> 6, rr = n & 63;
      char* rowp = (char*)dst + (((size_t)(bh * 32 + tq) * 64 + rr) << 7);
      const int swz = (rr & 7) << 4;
#pragma unroll
      for (int ni = 0; ni < 4; ++ni) {
        const unsigned u0 = cvtpk2(fmaf(acc[mi][ni][0], rstd, -mr), fmaf(acc[mi][ni][1], rstd, -mr));
        const unsigned u1 = cvtpk2(fmaf(acc[mi][ni][2], rstd, -mr), fmaf(acc[mi][ni][3], rstd, -mr));
        *(uint2*)(rowp + ((ni * 32 + d0b) ^ swz)) = make_uint2(u0, u1);
      }
    }
  }
}

// ---------- final projection: 128x64 tile (512 blocks = 2/CU), swapped acc, float4 out ----------
__global__ __launch_bounds__(256, 3) void gemm_out(const unsigned short* __restrict__ A,
                                                   const unsigned short* __restrict__ Wp,
                                                   float* __restrict__ C) {
  __shared__ char sA[16384], sB[8192];
  const int flat = blockIdx.x + (blockIdx.y << 4);  // grid (16,32)
  const int xcd = flat & 7, ii = flat >> 3;         // ii 0..63
  const int bm = xcd * 4 + (ii & 3), bn = ii >> 2;  // bm 0..31, bn 0..15
  const int tid = threadIdx.x, w = tid >> 6, lane = tid & 63;
  const int wm = w >> 1, wn = w & 1;
  f32x4 acc[4][2];
#pragma unroll
  for (int i = 0; i < 4; ++i)
#pragma unroll
    for (int j = 0; j < 2; ++j) acc[i][j] = (f32x4){0.f, 0.f, 0.f, 0.f};

  const char* aB = (const char*)A + ((size_t)(bm * 128 + (lane >> 3)) << 11) +
                   (((lane & 7) ^ (lane >> 3)) << 4);
  const char* bB = (const char*)Wp + ((size_t)(bn * 64 + (lane >> 3)) << 11) +
                   (((lane & 7) ^ (lane >> 3)) << 4);
  const int ldsBase = w * 1024;
  for (int kt = 0; kt < 16; ++kt) {
    const int ko = kt * 128;
#pragma unroll
    for (int c = 0; c < 4; ++c)
      gload16(aB + ((size_t)(c * 32 + w * 8) << 11) + ko, sA + c * 4096 + ldsBase);
#pragma unroll
    for (int c = 0; c < 2; ++c)
      gload16(bB + ((size_t)(c * 32 + w * 8) << 11) + ko, sB + c * 4096 + ldsBase);
    __syncthreads();
#pragma unroll
    for (int kk = 0; kk < 2; ++kk) {
      const int ch = ((kk * 4 + (lane >> 4)) ^ (lane & 7)) << 4;
      bf16x8 aF[4], bF[2];
#pragma unroll
      for (int mi = 0; mi < 4; ++mi)
        aF[mi] = *(const bf16x8*)(sA + (wm * 64 + mi * 16 + (lane & 15)) * 128 + ch);
#pragma unroll
      for (int ni = 0; ni < 2; ++ni)
        bF[ni] = *(const bf16x8*)(sB + (wn * 32 + ni * 16 + (lane & 15)) * 128 + ch);
#pragma unroll
      for (int mi = 0; mi < 4; ++mi)
#pragma unroll
        for (int ni = 0; ni < 2; ++ni)
          acc[mi][ni] = __builtin_amdgcn_mfma_f32_16x16x32_bf16(bF[ni], aF[mi], acc[mi][ni], 0, 0, 0);
    }
    __syncthreads();
  }
  const int m0 = bm * 128 + wm * 64 + (lane & 15);
  const int nb = bn * 64 + wn * 32 + ((lane >> 4) << 2);
#pragma unroll
  for (int mi = 0; mi < 4; ++mi)
#pragma unroll
    for (int ni = 0; ni < 2; ++ni) {
      const f32x4 v = acc[mi][ni];
      *(float4*)&C[(size_t)(m0 + mi * 16) * 1024 + nb + ni * 16] =
          make_float4(v[0], v[1], v[2], v[3]);
    }
}

// ---------- flash attention, swapped 32x32, in-register softmax, split-KV=4 ----------
// 2048 blocks, XCD-swizzled so each head's Q + KV quarters stay on one XCD L2.
__global__ __launch_bounds__(256, 4) void attn_fused(
    const unsigned short* __restrict__ Qp, const unsigned short* __restrict__ Kp,
    const unsigned short* __restrict__ Vp, unsigned short* __restrict__ Opart,
    float2* __restrict__ ML) {
  const int bid = blockIdx.x;
  const int xcd = bid & 7, idx = bid >> 3;
  const int bh = ((idx & 3) << 3) | xcd;  // bh % 8 == xcd
  const int quarter = (idx >> 2) & 3;
  const int qt = idx >> 4;  // 0..15
  __shared__ char sK[2][8192];
  __shared__ char sV[2][8192];
  const int tid = threadIdx.x, w = tid >> 6, lane = tid & 63;
  const int q5 = lane & 31, hi = lane >> 5;

  const char* qg = (const char*)Qp + ((size_t)bh * 32 + qt * 2) * 8192;
  const char* kg = (const char*)Kp + ((size_t)bh * 32 + quarter * 8) * 8192;
  const char* vg = (const char*)Vp + ((size_t)bh * 32 + quarter * 8) * 8192;

#pragma unroll
  for (int t = 0; t < 4; ++t)
    gload16(qg + (w * 4 + t) * 1024 + lane * 16, (char*)sK + (w * 4 + t) * 1024);
  __syncthreads();
  bf16x8 qf[4];
  {
    const int r128 = w * 32 + q5, tt = r128 >> 6, r = r128 & 63;
#pragma unroll
    for (int dc = 0; dc < 4; ++dc) {
      const int cb = dc * 32 + hi * 16;
      qf[dc] = *(const bf16x8*)((const char*)sK + tt * 8192 + r * 128 + (cb ^ ((r & 7) << 4)));
    }
  }
  __syncthreads();

#pragma unroll
  for (int t = 0; t < 2; ++t) {
    gload16(kg + (w * 2 + t) * 1024 + lane * 16, &sK[0][(w * 2 + t) * 1024]);
    gload16(vg + (w * 2 + t) * 1024 + lane * 16, &sV[0][(w * 2 + t) * 1024]);
  }

  f32x16 o0 = {0,0,0,0,0,0,0,0,0,0,0,0,0,0,0,0};
  f32x16 o1 = {0,0,0,0,0,0,0,0,0,0,0,0,0,0,0,0};
  float m = -1e30f, l = 0.f;

  for (int kt = 0; kt < 8; ++kt) {
    const int cur = kt & 1;
    __syncthreads();
    if (kt < 7) {
#pragma unroll
      for (int t = 0; t < 2; ++t) {
        gload16(kg + (size_t)(kt + 1) * 8192 + (w * 2 + t) * 1024 + lane * 16,
                &sK[cur ^ 1][(w * 2 + t) * 1024]);
        gload16(vg + (size_t)(kt + 1) * 8192 + (w * 2 + t) * 1024 + lane * 16,
                &sV[cur ^ 1][(w * 2 + t) * 1024]);
      }
    }
    // S^T = K * Q^T (log2 domain; scale*log2e folded into Q)
    f32x16 s0 = {0,0,0,0,0,0,0,0,0,0,0,0,0,0,0,0};
    f32x16 s1 = {0,0,0,0,0,0,0,0,0,0,0,0,0,0,0,0};
    __builtin_amdgcn_s_setprio(1);
#pragma unroll
    for (int dc = 0; dc < 4; ++dc) {
      const int cb = dc * 32 + hi * 16;
      const int ra = q5, rb = 32 + q5;
      bf16x8 kf0 = *(const bf16x8*)(&sK[cur][ra * 128 + (cb ^ ((ra & 7) << 4))]);
      bf16x8 kf1 = *(const bf16x8*)(&sK[cur][rb * 128 + (cb ^ ((rb & 7) << 4))]);
      s0 = __builtin_amdgcn_mfma_f32_32x32x16_bf16(kf0, qf[dc], s0, 0, 0, 0);
      s1 = __builtin_amdgcn_mfma_f32_32x32x16_bf16(kf1, qf[dc], s1, 0, 0, 0);
    }
    __builtin_amdgcn_s_setprio(0);
    // row max: 32 values via v_max3 tree (16 ops) + cross-half swap
    float tt[12];
#pragma unroll
    for (int r = 0; r < 10; ++r) {
      const float a = (3 * r) < 16 ? s0[(3 * r) & 15] : s1[(3 * r) & 15];
      const float b = (3 * r + 1) < 16 ? s0[(3 * r + 1) & 15] : s1[(3 * r + 1) & 15];
      const float c = (3 * r + 2) < 16 ? s0[(3 * r + 2) & 15] : s1[(3 * r + 2) & 15];
      tt[r] = max3(a, b, c);
    }
    tt[10] = s1[14]; tt[11] = s1[15];
    tt[0] = max3(tt[0], tt[1], tt[2]);
    tt[1] = max3(tt[3], tt[4], tt[5]);
    tt[2] = max3(tt[6], tt[7], tt[8]);
    tt[3] = max3(tt[9], tt[10], tt[11]);
    const float loc = fmaxf(max3(tt[0], tt[1], tt[2]), tt[3]);
    const float mx = fmaxf(loc, __shfl_xor(loc, 32));
    if (__any(mx > m + 8.f)) {  // defer-max (log2 units)
      const float mn = fmaxf(m, mx);
      const float corr = ex2(m - mn);
      l *= corr;
#pragma unroll
      for (int r = 0; r < 16; ++r) { o0[r] *= corr; o1[r] *= corr; }
      m = mn;
    }
    const float nm = -m;
    unsigned pk[4][4];
    float rs = 0.f;
#define DO_CHUNK(c, SV, B)                                      \
  {                                                             \
    float p0 = ex2(SV[B + 0] + nm);                             \
    float p1 = ex2(SV[B + 1] + nm);                             \
    float p2 = ex2(SV[B + 2] + nm);                             \
    float p3 = ex2(SV[B + 3] + nm);                             \
    float p4 = ex2(SV[B + 4] + nm);                             \
    float p5 = ex2(SV[B + 5] + nm);                             \
    float p6 = ex2(SV[B + 6] + nm);                             \
    float p7 = ex2(SV[B + 7] + nm);                             \
    rs += ((p0 + p1) + (p2 + p3)) + ((p4 + p5) + (p6 + p7));    \
    unsigned a0 = cvtpk2(p0, p1), a1 = cvtpk2(p2, p3);          \
    unsigned b0 = cvtpk2(p4, p5), b1 = cvtpk2(p6, p7);          \
    plswap(a0, b0);                                             \
    plswap(a1, b1);                                             \
    pk[c][0] = a0; pk[c][1] = a1; pk[c][2] = b0; pk[c][3] = b1; \
  }
    DO_CHUNK(0, s0, 0)
    DO_CHUNK(1, s0, 8)
    DO_CHUNK(2, s1, 0)
    DO_CHUNK(3, s1, 8)
#undef DO_CHUNK
    rs += __shfl_xor(rs, 32);
    l += rs;
    // O^T += V^T * P^T
    __builtin_amdgcn_s_setprio(1);
#pragma unroll
    for (int kk = 0; kk < 4; ++kk) {
      const int cb = kk * 32 + hi * 16;
      const int ra = q5, rb = 32 + q5;
      bf16x8 vf0 = *(const bf16x8*)(&sV[cur][ra * 128 + (cb ^ ((ra & 7) << 4))]);
      bf16x8 vf1 = *(const bf16x8*)(&sV[cur][rb * 128 + (cb ^ ((rb & 7) << 4))]);
      u32x4 pw = {pk[kk][0], pk[kk][1], pk[kk][2], pk[kk][3]};
      bf16x8 pb = __builtin_bit_cast(bf16x8, pw);
      o0 = __builtin_amdgcn_mfma_f32_32x32x16_bf16(vf0, pb, o0, 0, 0, 0);
      o1 = __builtin_amdgcn_mfma_f32_32x32x16_bf16(vf1, pb, o1, 0, 0, 0);
    }
    __builtin_amdgcn_s_setprio(0);
  }

  const float invl = 1.f / l;
  const int q = qt * 128 + w * 32 + q5;
  const size_t prow = (size_t)(quarter * 32 + bh) * 2048 + q;
  unsigned short* ob = Opart + prow * 64;
#pragma unroll
  for (int g = 0; g < 4; ++g) {
    unsigned d0 = cvtpk2(o0[4 * g + 0] * invl, o0[4 * g + 1] * invl);
    unsigned d1 = cvtpk2(o0[4 * g + 2] * invl, o0[4 * g + 3] * invl);
    *(uint2*)(ob + 8 * g + 4 * hi) = make_uint2(d0, d1);
    unsigned e0 = cvtpk2(o1[4 * g + 0] * invl, o1[4 * g + 1] * invl);
    unsigned e1 = cvtpk2(o1[4 * g + 2] * invl, o1[4 * g + 3] * invl);
    *(uint2*)(ob + 32 + 8 * g + 4 * hi) = make_uint2(e0, e1);
  }
  if (hi == 0) ML[prow] = make_float2(m, l);
}

// ---------- merge the four KV-quarter partials ----------
__global__ __launch_bounds__(256) void attn_merge(const unsigned short* __restrict__ Op,
                                                  const float2* __restrict__ ML,
                                                  unsigned short* __restrict__ O) {
  const int gid = blockIdx.x * 256 + threadIdx.x;
  const int row = gid >> 3, sub = gid & 7;
  float2 ml[4];
  float mm = -1e30f;
#pragma unroll
  for (int p = 0; p < 4; ++p) {
    ml[p] = ML[p * 65536 + row];
    mm = fmaxf(mm, ml[p].x);
  }
  float wgt[4], wsum = 0.f;
#pragma unroll
  for (int p = 0; p < 4; ++p) {
    wgt[p] = ml[p].y * ex2(ml[p].x - mm);
    wsum += wgt[p];
  }
  const float inv = 1.f / wsum;
  float r[8] = {0.f, 0.f, 0.f, 0.f, 0.f, 0.f, 0.f, 0.f};
#pragma unroll
  for (int p = 0; p < 4; ++p) {
    const uint4 a = *(const uint4*)(Op + ((size_t)(p * 65536) + row) * 64 + sub * 8);
    const unsigned av[4] = {a.x, a.y, a.z, a.w};
#pragma unroll
    for (int j = 0; j < 4; ++j) {
      r[2 * j] += wgt[p] * bf2f((unsigned short)(av[j] & 0xffff));
      r[2 * j + 1] += wgt[p] * bf2f((unsigned short)(av[j] >> 16));
    }
  }
  unsigned ov[4];
#pragma unroll
  for (int j = 0; j < 4; ++j)
    ov[j] = cvtpk2(r[2 * j] * inv, r[2 * j + 1] * inv);
  const int bh = row >> 11, q = row & 2047, bb = bh >> 4, h = bh & 15;
  *(uint4*)(O + ((size_t)(bb * 2048 + q) * 1024 + h * 64 + sub * 8)) =
      make_uint4(ov[0], ov[1], ov[2], ov[3]);
}

// ---------- launch ----------
extern "C" void kernel_launch(void* const* d_in, const int* in_sizes, int n_in,
                              void* d_out, int out_size, void* d_ws, size_t ws_size,
                              hipStream_t stream) {
  const float* xq = (const float*)d_in[0];
  const float* xk = (const float*)d_in[1];
  const float* xv = (const float*)d_in[2];
  const float* wq = (const float*)d_in[3];
  const float* wk = (const float*)d_in[4];
  const float* wv = (const float*)d_in[5];
  const float* wp = (const float*)d_in[6];

  const size_t NX = 4194304;  // B*N*D
  const size_t NW = 1048576;  // D*D
  unsigned short* base = (unsigned short*)d_ws;
  unsigned short* xqb = base;                 // [0, 4M)
  unsigned short* xkb = base + NX;            // [4M, 8M)
  unsigned short* xvb = base + 2 * NX;        // [8M, 12M)
  unsigned short* wqb = base + 3 * NX;        // [12M, 13M)
  unsigned short* wkb = wqb + NW;             // [13M, 14M)
  unsigned short* wvb = wkb + NW;             // [14M, 15M) + 1M pad to 16M
  unsigned short* wpb = base + 3 * NX + 4 * NW;  // [16M, 17M) — survives opart
  unsigned short* qh = wpb + NW;              // [17M, 21M)
  unsigned short* kh = qh + NX;               // [21M, 25M)
  unsigned short* vt = kh + NX;               // [25M, 29M)
  unsigned short* obf = vt + NX;              // [29M, 33M)
  float2* ml = (float2*)(obf + NX);           // [33M, 34M)
  unsigned short* opart = base;               // [0, 16M) aliases dead x/w buffers

  cvt7<<<dim3(512, 7), 256, 0, stream>>>(xq, xk, xv, wq, wk, wv, wp, (ushort4*)xqb,
                                         (ushort4*)xkb, (ushort4*)xvb, (ushort4*)wqb,
                                         (ushort4*)wkb, (ushort4*)wvb, (ushort4*)wpb,
                                         (int)(NX / 4), (int)(NW / 4));

  gemm_qkv<<<dim3(8, 32, 3), 256, 0, stream>>>(xqb, xkb, xvb, wqb, wkb, wvb, qh, kh, vt);

  attn_fused<<<2048, 256, 0, stream>>>(qh, kh, vt, opart, ml);
  attn_merge<<<2048, 256, 0, stream>>>(opart, ml, obf);

  gemm_out<<<dim3(16, 32), 256, 0, stream>>>(obf, wpb, (float*)d_out);
}